// Round 7
// baseline (358.985 us; speedup 1.0000x reference)
//
#include <hip/hip_runtime.h>
#include <math.h>

#define DD   2048
#define TEMP 0.07f
#define GRID_GEMM 1024
#define NROWS 16          // feature rows per block (gemm)
#define DC    128         // k-chunk per LDS stage
#define KW    512         // k-range per wave
#define NCHW  (KW / DC)   // 4 chunks per wave

typedef __attribute__((ext_vector_type(8))) short short8;
typedef __attribute__((ext_vector_type(4))) float f32x4;

// ws layout (float offsets):
//   fA   [65536]  (131072 ushort: f in MFMA A-frag order [qt][ksg][lane][j])
//   blab [64]     at 65536 (int)
//   Wm   [1024*64] at 65600
//   Ws   [1024*64] at 131136
//   Wp   [1024*64] at 196672

__device__ __forceinline__ unsigned short to_bf16(float x) {
    union { float f; unsigned u; } v; v.f = x;
    unsigned r = v.u + 0x7fffu + ((v.u >> 16) & 1u);   // RNE
    return (unsigned short)(r >> 16);
}

// K0: f [64][2048] fp32 -> fA bf16 in A-fragment order; gather batch labels.
// A-frag (16x16x32): m = lane&15, k = ksg*32 + (lane>>4)*8 + j
__global__ __launch_bounds__(256) void k_prep(const float* __restrict__ f,
                                              const int* __restrict__ indexes,
                                              const int* __restrict__ labels,
                                              unsigned short* __restrict__ fA,
                                              int* __restrict__ blab) {
    const int q  = blockIdx.x;    // 0..63
    const int kc = threadIdx.x;   // k = kc*8
    const float* src = f + (size_t)q * DD + kc * 8;
    float4 a = *(const float4*)src;
    float4 b = *(const float4*)(src + 4);
    uint4 u;
    u.x = (unsigned)to_bf16(a.x) | ((unsigned)to_bf16(a.y) << 16);
    u.y = (unsigned)to_bf16(a.z) | ((unsigned)to_bf16(a.w) << 16);
    u.z = (unsigned)to_bf16(b.x) | ((unsigned)to_bf16(b.y) << 16);
    u.w = (unsigned)to_bf16(b.z) | ((unsigned)to_bf16(b.w) << 16);
    const int w = q >> 4, ksg = kc >> 2;
    const int lane = (q & 15) | ((kc & 3) << 4);
    *(uint4*)(fA + ((size_t)(w * 64 + ksg) * 64 + lane) * 8) = u;
    if (q == 0 && kc < 64) blab[kc] = labels[indexes[kc]];
}

// K1a: READ-ONLY gemm. 16 rows/block, k split across waves (wave w owns
// [w*512, w*512+512)). No out stores, no shuffles, no k-loop barriers.
// Per chunk: load feat -> bf16 -> own-wave LDS B-frags (in-order DS) ->
// MFMA vs all 4 q-tiles of fA. End: cross-wave accS combine + shfl_xor
// masked online reduce -> per-block partials.
__global__ __launch_bounds__(256, 4) void k_gemm(const float* __restrict__ feat,
                                                 const unsigned short* __restrict__ fA,
                                                 const int* __restrict__ labels,
                                                 const int* __restrict__ blab,
                                                 float* __restrict__ Wm,
                                                 float* __restrict__ Ws,
                                                 float* __restrict__ Wp) {
    __shared__ uint4 Bf[4][256];            // per-wave 4KB B-frag region; reused as accS
    __shared__ int lab_s[16], blab_s[64];

    const int tid = threadIdx.x;
    const int w   = tid >> 6;               // wave id = k-quarter
    const int l   = tid & 63;               // lane
    const int n0  = blockIdx.x * NROWS;

    if (tid < 16) lab_s[tid] = labels[n0 + tid];
    if (tid >= 64 && tid < 128) blab_s[tid - 64] = blab[tid - 64];

    const int rh = l >> 5;                  // row parity within pass
    const int c  = l & 31;                  // float4 column within 128-k chunk
    const int kw = w * KW;                  // wave k-base (floats)
    const uint4* __restrict__ fA4 = (const uint4*)fA;

    f32x4 acc[4];
#pragma unroll
    for (int qt = 0; qt < 4; ++qt) acc[qt] = (f32x4){0.f, 0.f, 0.f, 0.f};

    float4 Fa[8];
#pragma unroll
    for (int p = 0; p < 8; ++p)
        Fa[p] = *(const float4*)&feat[(size_t)(n0 + p * 2 + rh) * DD + kw + 4 * c];

#pragma unroll
    for (int ch = 0; ch < NCHW; ++ch) {
        const int k0 = kw + ch * DC;
#pragma unroll
        for (int p = 0; p < 8; ++p) {
            const int r = p * 2 + rh;
            float4 F = Fa[p];
            if (ch + 1 < NCHW)              // consume-replace prefetch
                Fa[p] = *(const float4*)&feat[(size_t)(n0 + r) * DD + k0 + DC + 4 * c];
            unsigned u0 = (unsigned)to_bf16(F.x) | ((unsigned)to_bf16(F.y) << 16);
            unsigned u1 = (unsigned)to_bf16(F.z) | ((unsigned)to_bf16(F.w) << 16);
            int ks    = c >> 3;
            int lanef = r | (((c >> 1) & 3) << 4);
            ((uint2*)&Bf[w][0])[(ks * 64 + lanef) * 2 + (c & 1)] = make_uint2(u0, u1);
        }
        // same-wave DS ops are in-order; lgkmcnt(0) guarantees writes landed
        asm volatile("s_waitcnt lgkmcnt(0)" ::: "memory");
#pragma unroll
        for (int ks = 0; ks < 4; ++ks) {
            uint4 braw = Bf[w][ks * 64 + l];
            const int ksg = w * 16 + ch * 4 + ks;
#pragma unroll
            for (int qt = 0; qt < 4; ++qt) {
                uint4 araw = fA4[(size_t)(qt * 64 + ksg) * 64 + l];
                acc[qt] = __builtin_amdgcn_mfma_f32_16x16x32_bf16(
                    __builtin_bit_cast(short8, araw), __builtin_bit_cast(short8, braw),
                    acc[qt], 0, 0, 0);
            }
        }
    }

    // ---- combine k-partials across waves (reuse Bf LDS as accS) ----
    float* accS = (float*)&Bf[0][0];        // [src_wave][qt][reg][lane], 16 KB
#pragma unroll
    for (int qt = 0; qt < 4; ++qt)
#pragma unroll
        for (int r = 0; r < 4; ++r)
            accS[((w * 4 + qt) * 4 + r) * 64 + l] = acc[qt][r];
    __syncthreads();

    const float invT = 1.0f / TEMP;
    const int nl = l & 15;
    const int g  = l >> 4;
    const int lab = lab_s[nl];
#pragma unroll
    for (int r = 0; r < 4; ++r) {
        float y = accS[((0 * 4 + w) * 4 + r) * 64 + l]
                + accS[((1 * 4 + w) * 4 + r) * 64 + l]
                + accS[((2 * 4 + w) * 4 + r) * 64 + l]
                + accS[((3 * 4 + w) * 4 + r) * 64 + l];
        y *= invT;
        const int q = w * 16 + g * 4 + r;
        const bool match = (lab == blab_s[q]);
        float M = match ? -3.4e38f : y;
        float S = match ? 0.f : 1.f;
        float P = match ? y : 3.4e38f;
#pragma unroll
        for (int d = 1; d < 16; d <<= 1) {
            float Mo = __shfl_xor(M, d, 64);
            float So = __shfl_xor(S, d, 64);
            float Po = __shfl_xor(P, d, 64);
            float Mn = fmaxf(M, Mo);
            S = S * __expf(M - Mn) + So * __expf(Mo - Mn);
            M = Mn;
            P = fminf(P, Po);
        }
        if (nl == 0) {
            Wm[blockIdx.x * 64 + q] = M;
            Ws[blockIdx.x * 64 + q] = S;
            Wp[blockIdx.x * 64 + q] = P;
        }
    }
}

// K1b: pure shifted copy out[i+1] = feat[i]. All-aligned scheme: per 8
// floats, 2 aligned quad loads + 1 scalar overlap load (L1-hit), 2 aligned
// nontemporal quad stores (ext_vector f32x4 — clang vector type).
__global__ __launch_bounds__(256) void k_copy(const float* __restrict__ feat,
                                              float* __restrict__ out) {
    const int t = blockIdx.x * 256 + threadIdx.x;    // 0..1048575
    float  s[4];
    float4 q0[4], q1[4];
#pragma unroll
    for (int u = 0; u < 4; ++u) {
        const size_t m8 = (size_t)u * 1048576 + t;   // 8-float unit index
        const size_t f0 = m8 * 8;
        long si = (long)f0 - 1;
        if (si < 0) si = 0;                          // unit 0: s=feat[0] lands at out[0] (loss slot, overwritten)
        s[u]  = feat[si];
        q0[u] = *(const float4*)(feat + f0);
        q1[u] = *(const float4*)(feat + f0 + 4);
    }
#pragma unroll
    for (int u = 0; u < 4; ++u) {
        const size_t m8 = (size_t)u * 1048576 + t;
        const size_t f0 = m8 * 8;
        f32x4 a = {s[u],    q0[u].x, q0[u].y, q0[u].z};
        f32x4 b = {q0[u].w, q1[u].x, q1[u].y, q1[u].z};
        __builtin_nontemporal_store(a, (f32x4*)(out + f0));
        __builtin_nontemporal_store(b, (f32x4*)(out + f0 + 4));
    }
}

// K2: combine 1024 partials/query -> loss at out[0]
__global__ __launch_bounds__(256) void k_loss(const float* __restrict__ Wm,
                                              const float* __restrict__ Ws,
                                              const float* __restrict__ Wp,
                                              float* __restrict__ out) {
    __shared__ float Lm[4][64], Ls[4][64], Lp[4][64];
    const int t = threadIdx.x, q = t & 63, ci = t >> 6;
    float M = -3.4e38f, S = 0.f, P = 3.4e38f;
    for (int i = ci * 256; i < ci * 256 + 256; ++i) {
        float m = Wm[i * 64 + q], s = Ws[i * 64 + q], p = Wp[i * 64 + q];
        if (m > M) { S = S * __expf(M - m) + s; M = m; }
        else       { S += s * __expf(m - M); }
        P = fminf(P, p);
    }
    Lm[ci][q] = M; Ls[ci][q] = S; Lp[ci][q] = P;
    __syncthreads();
    if (t < 64) {
        M = -3.4e38f; S = 0.f; P = 3.4e38f;
#pragma unroll
        for (int i = 0; i < 4; ++i) {
            float m = Lm[i][t], s = Ls[i][t], p = Lp[i][t];
            if (m > M) { S = S * __expf(M - m) + s; M = m; }
            else       { S += s * __expf(m - M); }
            P = fminf(P, p);
        }
        float Mall = fmaxf(M, P);
        float lse  = Mall + logf(S * __expf(M - Mall) + __expf(P - Mall));
        float loss = lse - P;
        for (int off = 32; off > 0; off >>= 1) loss += __shfl_down(loss, off, 64);
        if (t == 0) out[0] = loss * (1.0f / 64.0f);
    }
}

// K3: momentum update of the 64 indexed rows (last-wins on duplicates)
__global__ __launch_bounds__(256) void k_update(const float* __restrict__ feat,
                                                const float* __restrict__ f_weak,
                                                const int* __restrict__ indexes,
                                                float* __restrict__ out) {
    const int b = blockIdx.x;
    const int idx = indexes[b];
    for (int b2 = b + 1; b2 < 64; ++b2)
        if (indexes[b2] == idx) return;     // uniform over block
    const int tid = threadIdx.x;
    float wv[8];
    float ss = 0.f;
#pragma unroll
    for (int k = 0; k < 8; ++k) {
        int d = tid + 256 * k;
        float v = feat[(size_t)idx * DD + d] * 0.2f + f_weak[(size_t)b * DD + d] * 0.8f;
        wv[k] = v;
        ss += v * v;
    }
    for (int off = 32; off > 0; off >>= 1) ss += __shfl_down(ss, off, 64);
    __shared__ float red[4];
    if ((tid & 63) == 0) red[tid >> 6] = ss;
    __syncthreads();
    float tot = red[0] + red[1] + red[2] + red[3];
    float inv = 1.0f / fmaxf(sqrtf(tot), 1e-12f);
#pragma unroll
    for (int k = 0; k < 8; ++k) {
        int d = tid + 256 * k;
        out[1 + (size_t)idx * DD + d] = wv[k] * inv;
    }
}

extern "C" void kernel_launch(void* const* d_in, const int* in_sizes, int n_in,
                              void* d_out, int out_size, void* d_ws, size_t ws_size,
                              hipStream_t stream) {
    const float* f       = (const float*)d_in[0];
    const float* f_weak  = (const float*)d_in[1];
    const int*   indexes = (const int*)d_in[2];
    const float* feat    = (const float*)d_in[3];
    const int*   labels  = (const int*)d_in[4];
    float* out = (float*)d_out;
    float* ws  = (float*)d_ws;

    unsigned short* fA = (unsigned short*)ws;          // 131072 ushort
    int*   blab = (int*)(ws + 65536);
    float* Wm   = ws + 65600;
    float* Wsm  = ws + 131136;
    float* Wp   = ws + 196672;

    k_prep<<<64, 256, 0, stream>>>(f, indexes, labels, fA, blab);
    k_gemm<<<GRID_GEMM, 256, 0, stream>>>(feat, fA, labels, blab, Wm, Wsm, Wp);
    k_copy<<<4096, 256, 0, stream>>>(feat, out);
    k_loss<<<1, 256, 0, stream>>>(Wm, Wsm, Wp, out);
    k_update<<<64, 256, 0, stream>>>(feat, f_weak, indexes, out);
}

// Round 8
// 322.272 us; speedup vs baseline: 1.1139x; 1.1139x over previous
//
#include <hip/hip_runtime.h>
#include <math.h>

#define DD   2048
#define TEMP 0.07f
#define GRID_GEMM 256
#define NROWS 64          // feature rows per block (gemm)
#define KW    512         // k-range per wave (4 chunks of 128)

typedef __attribute__((ext_vector_type(8))) short short8;
typedef __attribute__((ext_vector_type(4))) float f32x4;

// ws layout (float offsets):
//   fA   [65536]  (131072 ushort: f in MFMA A-frag order [qt][ksg][lane][j])
//   blab [64]     at 65536 (int)
//   Wm   [256*64] at 65600
//   Ws   [256*64] at 131136
//   Wp   [256*64] at 196672

__device__ __forceinline__ unsigned short to_bf16(float x) {
    union { float f; unsigned u; } v; v.f = x;
    unsigned r = v.u + 0x7fffu + ((v.u >> 16) & 1u);   // RNE
    return (unsigned short)(r >> 16);
}

// bank-spread swizzle on uint4 index within a wave's 16KB B-frag region
#define SWZ4(I) ((I) ^ (((I) >> 4) & 7))

// K0: f [64][2048] fp32 -> fA bf16 in A-fragment order; gather batch labels.
__global__ __launch_bounds__(256) void k_prep(const float* __restrict__ f,
                                              const int* __restrict__ indexes,
                                              const int* __restrict__ labels,
                                              unsigned short* __restrict__ fA,
                                              int* __restrict__ blab) {
    const int q  = blockIdx.x;    // 0..63
    const int kc = threadIdx.x;   // k = kc*8
    const float* src = f + (size_t)q * DD + kc * 8;
    float4 a = *(const float4*)src;
    float4 b = *(const float4*)(src + 4);
    uint4 u;
    u.x = (unsigned)to_bf16(a.x) | ((unsigned)to_bf16(a.y) << 16);
    u.y = (unsigned)to_bf16(a.z) | ((unsigned)to_bf16(a.w) << 16);
    u.z = (unsigned)to_bf16(b.x) | ((unsigned)to_bf16(b.y) << 16);
    u.w = (unsigned)to_bf16(b.z) | ((unsigned)to_bf16(b.w) << 16);
    const int w = q >> 4, ksg = kc >> 2;
    const int lane = (q & 15) | ((kc & 3) << 4);
    *(uint4*)(fA + ((size_t)(w * 64 + ksg) * 64 + lane) * 8) = u;
    if (q == 0 && kc < 64) blab[kc] = labels[indexes[kc]];
}

// K1a: READ-ONLY gemm, fA amortized over 64 rows/block (grid=256, 1 blk/CU).
// Wave w owns k-quarter [w*512,(w+1)*512). Per 128-k chunk: 4 groups of
// 16 rows streamed (float4 loads, 1 group in flight ahead), bf16 -> swizzled
// LDS B-frags; fA chunk loads issued at chunk start (L2-hot, hidden under
// streaming); then 16 ds_reads + 64 MFMAs. No k-loop barriers.
__global__ __launch_bounds__(256) void k_gemm(const float* __restrict__ feat,
                                              const unsigned short* __restrict__ fA,
                                              const int* __restrict__ labels,
                                              const int* __restrict__ blab,
                                              float* __restrict__ Wm,
                                              float* __restrict__ Ws,
                                              float* __restrict__ Wp) {
    __shared__ uint4 Bf[4][1024];           // per-wave 16KB B-frag region; reused as accS
    __shared__ int lab_s[64], blab_s[64];

    const int tid = threadIdx.x;
    const int w   = tid >> 6;               // wave id = k-quarter
    const int l   = tid & 63;               // lane
    const int n0  = blockIdx.x * NROWS;

    if (tid < 64) lab_s[tid] = labels[n0 + tid];
    if (tid >= 64 && tid < 128) blab_s[tid - 64] = blab[tid - 64];

    const int rh = l >> 5;                  // row parity
    const int c  = l & 31;                  // float4 column within 128-k chunk
    const int kw = w * KW;                  // wave k-base (floats)
    const uint4* __restrict__ fA4 = (const uint4*)fA;
    uint2* __restrict__ Bw2 = (uint2*)&Bf[w][0];

    f32x4 acc[4][4];                        // [qt][nt]
#pragma unroll
    for (int qt = 0; qt < 4; ++qt)
#pragma unroll
        for (int nt = 0; nt < 4; ++nt) acc[qt][nt] = (f32x4){0.f, 0.f, 0.f, 0.f};

    // group gi = ch*4 + g : rows g*16 .. g*16+15 of chunk ch
#define LOADG(buf, gj)                                                         \
    {                                                                          \
        const int ch2 = (gj) >> 2, g2 = (gj) & 3;                              \
        _Pragma("unroll")                                                      \
        for (int pp = 0; pp < 8; ++pp)                                         \
            buf[pp] = *(const float4*)&feat[(size_t)(n0 + g2 * 16 + pp * 2 + rh) * DD \
                                            + kw + ch2 * 128 + 4 * c];         \
    }
#define PROCG(buf, gi_)                                                        \
    {                                                                          \
        const int g2 = (gi_) & 3;           /* = nt */                         \
        _Pragma("unroll")                                                      \
        for (int pp = 0; pp < 8; ++pp) {                                       \
            float4 F = buf[pp];                                                \
            unsigned u0 = (unsigned)to_bf16(F.x) | ((unsigned)to_bf16(F.y) << 16); \
            unsigned u1 = (unsigned)to_bf16(F.z) | ((unsigned)to_bf16(F.w) << 16); \
            const int ks = c >> 3;                                             \
            const int lanef = (pp * 2 + rh) | (((c >> 1) & 3) << 4);           \
            const int I4 = (g2 * 4 + ks) * 64 + lanef;                         \
            Bw2[SWZ4(I4) * 2 + (c & 1)] = make_uint2(u0, u1);                  \
        }                                                                      \
    }

    float4 FbA[8], FbB[8];
    uint4  ar[16];
    LOADG(FbA, 0);
#pragma unroll
    for (int gi = 0; gi < 16; ++gi) {
        const int ch = gi >> 2;
        if ((gi & 3) == 0) {                // fA loads for this chunk (L2-hot)
#pragma unroll
            for (int ks = 0; ks < 4; ++ks)
#pragma unroll
                for (int qt = 0; qt < 4; ++qt)
                    ar[ks * 4 + qt] =
                        fA4[(size_t)(qt * 64 + (w * 16 + ch * 4 + ks)) * 64 + l];
        }
        if (gi + 1 < 16) {                  // stream next group 1 ahead
            if (gi & 1) { LOADG(FbA, gi + 1); }
            else        { LOADG(FbB, gi + 1); }
        }
        if (gi & 1) { PROCG(FbB, gi); }
        else        { PROCG(FbA, gi); }
        if ((gi & 3) == 3) {                // chunk complete -> MFMA
            asm volatile("s_waitcnt lgkmcnt(0)" ::: "memory");
#pragma unroll
            for (int ks = 0; ks < 4; ++ks) {
                uint4 br[4];
#pragma unroll
                for (int nt = 0; nt < 4; ++nt)
                    br[nt] = Bf[w][SWZ4((nt * 4 + ks) * 64 + l)];
#pragma unroll
                for (int nt = 0; nt < 4; ++nt)
#pragma unroll
                    for (int qt = 0; qt < 4; ++qt)
                        acc[qt][nt] = __builtin_amdgcn_mfma_f32_16x16x32_bf16(
                            __builtin_bit_cast(short8, ar[ks * 4 + qt]),
                            __builtin_bit_cast(short8, br[nt]), acc[qt][nt], 0, 0, 0);
            }
        }
    }
#undef LOADG
#undef PROCG

    // ---- combine k-partials across waves (reuse Bf LDS as accS, 64 KB) ----
    float* accS = (float*)&Bf[0][0];        // [src_wave][qt][nt][r][lane]
#pragma unroll
    for (int qt = 0; qt < 4; ++qt)
#pragma unroll
        for (int nt = 0; nt < 4; ++nt)
#pragma unroll
            for (int r = 0; r < 4; ++r)
                accS[(((w * 4 + qt) * 4 + nt) * 4 + r) * 64 + l] = acc[qt][nt][r];
    __syncthreads();

    // wave w takes q-tile w; masked online reduce over 64 rows
    const float invT = 1.0f / TEMP;
    const int nl = l & 15;
    const int g  = l >> 4;
#pragma unroll
    for (int r = 0; r < 4; ++r) {
        const int q  = w * 16 + g * 4 + r;
        const int bl = blab_s[q];
        float M = -3.4e38f, S = 0.f, P = 3.4e38f;
#pragma unroll
        for (int nt = 0; nt < 4; ++nt) {
            float y = accS[(((0 * 4 + w) * 4 + nt) * 4 + r) * 64 + l]
                    + accS[(((1 * 4 + w) * 4 + nt) * 4 + r) * 64 + l]
                    + accS[(((2 * 4 + w) * 4 + nt) * 4 + r) * 64 + l]
                    + accS[(((3 * 4 + w) * 4 + nt) * 4 + r) * 64 + l];
            y *= invT;
            const bool match = (lab_s[nt * 16 + nl] == bl);
            const float ym = match ? -3.4e38f : y;
            const float s1 = match ? 0.f : 1.f;
            if (ym > M) { S = S * __expf(M - ym) + s1; M = ym; }
            else        { S += s1 * __expf(ym - M); }
            P = fminf(P, match ? y : 3.4e38f);
        }
#pragma unroll
        for (int d = 1; d < 16; d <<= 1) {
            float Mo = __shfl_xor(M, d, 64);
            float So = __shfl_xor(S, d, 64);
            float Po = __shfl_xor(P, d, 64);
            float Mn = fmaxf(M, Mo);
            S = S * __expf(M - Mn) + So * __expf(Mo - Mn);
            M = Mn;
            P = fminf(P, Po);
        }
        if (nl == 0) {
            Wm[blockIdx.x * 64 + q] = M;
            Ws[blockIdx.x * 64 + q] = S;
            Wp[blockIdx.x * 64 + q] = P;
        }
    }
}

// K1b: pure shifted copy out[i+1] = feat[i] (+ the final tail element).
__global__ __launch_bounds__(256) void k_copy(const float* __restrict__ feat,
                                              float* __restrict__ out) {
    const int t = blockIdx.x * 256 + threadIdx.x;    // 0..1048575
    float  s[4];
    float4 q0[4], q1[4];
#pragma unroll
    for (int u = 0; u < 4; ++u) {
        const size_t m8 = (size_t)u * 1048576 + t;   // 8-float unit index
        const size_t f0 = m8 * 8;
        long si = (long)f0 - 1;
        if (si < 0) si = 0;                          // unit 0 head lands at out[0] (loss slot, overwritten)
        s[u]  = feat[si];
        q0[u] = *(const float4*)(feat + f0);
        q1[u] = *(const float4*)(feat + f0 + 4);
    }
#pragma unroll
    for (int u = 0; u < 4; ++u) {
        const size_t f0 = ((size_t)u * 1048576 + t) * 8;
        f32x4 a = {s[u],    q0[u].x, q0[u].y, q0[u].z};
        f32x4 b = {q0[u].w, q1[u].x, q1[u].y, q1[u].z};
        __builtin_nontemporal_store(a, (f32x4*)(out + f0));
        __builtin_nontemporal_store(b, (f32x4*)(out + f0 + 4));
    }
    if (t == 1048575)                                // last out element
        out[(size_t)DD * 16384] = feat[(size_t)DD * 16384 - 1];
}

// K2: combine 256 partials/query -> loss at out[0]
__global__ __launch_bounds__(256) void k_loss(const float* __restrict__ Wm,
                                              const float* __restrict__ Ws,
                                              const float* __restrict__ Wp,
                                              float* __restrict__ out) {
    __shared__ float Lm[4][64], Ls[4][64], Lp[4][64];
    const int t = threadIdx.x, q = t & 63, ci = t >> 6;
    float M = -3.4e38f, S = 0.f, P = 3.4e38f;
    for (int i = ci * 64; i < ci * 64 + 64; ++i) {
        float m = Wm[i * 64 + q], s = Ws[i * 64 + q], p = Wp[i * 64 + q];
        if (m > M) { S = S * __expf(M - m) + s; M = m; }
        else       { S += s * __expf(m - M); }
        P = fminf(P, p);
    }
    Lm[ci][q] = M; Ls[ci][q] = S; Lp[ci][q] = P;
    __syncthreads();
    if (t < 64) {
        M = -3.4e38f; S = 0.f; P = 3.4e38f;
#pragma unroll
        for (int i = 0; i < 4; ++i) {
            float m = Lm[i][t], s = Ls[i][t], p = Lp[i][t];
            if (m > M) { S = S * __expf(M - m) + s; M = m; }
            else       { S += s * __expf(m - M); }
            P = fminf(P, p);
        }
        float Mall = fmaxf(M, P);
        float lse  = Mall + logf(S * __expf(M - Mall) + __expf(P - Mall));
        float loss = lse - P;
        for (int off = 32; off > 0; off >>= 1) loss += __shfl_down(loss, off, 64);
        if (t == 0) out[0] = loss * (1.0f / 64.0f);
    }
}

// K3: momentum update of the 64 indexed rows (last-wins on duplicates)
__global__ __launch_bounds__(256) void k_update(const float* __restrict__ feat,
                                                const float* __restrict__ f_weak,
                                                const int* __restrict__ indexes,
                                                float* __restrict__ out) {
    const int b = blockIdx.x;
    const int idx = indexes[b];
    for (int b2 = b + 1; b2 < 64; ++b2)
        if (indexes[b2] == idx) return;     // uniform over block
    const int tid = threadIdx.x;
    float wv[8];
    float ss = 0.f;
#pragma unroll
    for (int k = 0; k < 8; ++k) {
        int d = tid + 256 * k;
        float v = feat[(size_t)idx * DD + d] * 0.2f + f_weak[(size_t)b * DD + d] * 0.8f;
        wv[k] = v;
        ss += v * v;
    }
    for (int off = 32; off > 0; off >>= 1) ss += __shfl_down(ss, off, 64);
    __shared__ float red[4];
    if ((tid & 63) == 0) red[tid >> 6] = ss;
    __syncthreads();
    float tot = red[0] + red[1] + red[2] + red[3];
    float inv = 1.0f / fmaxf(sqrtf(tot), 1e-12f);
#pragma unroll
    for (int k = 0; k < 8; ++k) {
        int d = tid + 256 * k;
        out[1 + (size_t)idx * DD + d] = wv[k] * inv;
    }
}

extern "C" void kernel_launch(void* const* d_in, const int* in_sizes, int n_in,
                              void* d_out, int out_size, void* d_ws, size_t ws_size,
                              hipStream_t stream) {
    const float* f       = (const float*)d_in[0];
    const float* f_weak  = (const float*)d_in[1];
    const int*   indexes = (const int*)d_in[2];
    const float* feat    = (const float*)d_in[3];
    const int*   labels  = (const int*)d_in[4];
    float* out = (float*)d_out;
    float* ws  = (float*)d_ws;

    unsigned short* fA = (unsigned short*)ws;          // 131072 ushort
    int*   blab = (int*)(ws + 65536);
    float* Wm   = ws + 65600;
    float* Wsm  = ws + 131136;
    float* Wp   = ws + 196672;

    k_prep<<<64, 256, 0, stream>>>(f, indexes, labels, fA, blab);
    k_gemm<<<GRID_GEMM, 256, 0, stream>>>(feat, fA, labels, blab, Wm, Wsm, Wp);
    k_copy<<<4096, 256, 0, stream>>>(feat, out);
    k_loss<<<1, 256, 0, stream>>>(Wm, Wsm, Wp, out);
    k_update<<<64, 256, 0, stream>>>(feat, f_weak, indexes, out);
}